// Round 6
// baseline (771.601 us; speedup 1.0000x reference)
//
#include <hip/hip_runtime.h>

// Problem constants
static constexpr int NN   = 50000;
static constexpr int EE   = 800000;
static constexpr int GG   = 256;
static constexpr int NBLK = (NN + 255) / 256;   // 196
static constexpr int PCH  = 16;                 // pooling chunks per graph
static constexpr int NPB  = 32;                 // nodes per aggs block

// ---------- helpers ----------
__device__ __forceinline__ int lowerb(const int* __restrict__ b, int n, int v) {
    int lo = 0, hi = n;
    while (lo < hi) { int m = (lo + hi) >> 1; if (b[m] < v) lo = m + 1; else hi = m; }
    return lo;
}

// ---------- CSR build (by target node = col) ----------
__global__ void count_k(const int* __restrict__ ei, int* __restrict__ cnt)
{
    int e = blockIdx.x * 256 + threadIdx.x;
    if (e < EE) atomicAdd(&cnt[ei[EE + e]], 1);
}

__global__ __launch_bounds__(256) void bsum_k(const int* __restrict__ cnt, int* __restrict__ bsum)
{
    __shared__ int s[256];
    int b = blockIdx.x, t = threadIdx.x;
    int i = b * 256 + t;
    s[t] = (i < NN) ? cnt[i] : 0;
    __syncthreads();
    #pragma unroll
    for (int off = 128; off > 0; off >>= 1) {
        if (t < off) s[t] += s[t + off];
        __syncthreads();
    }
    if (t == 0) bsum[b] = s[0];
}

__global__ __launch_bounds__(256) void scanb_k(const int* __restrict__ bsum, int* __restrict__ boff)
{
    __shared__ int s[256];
    int t = threadIdx.x;
    int v = (t < NBLK) ? bsum[t] : 0;
    s[t] = v;
    __syncthreads();
    #pragma unroll
    for (int off = 1; off < 256; off <<= 1) {
        int add = (t >= off) ? s[t - off] : 0;
        __syncthreads();
        s[t] += add;
        __syncthreads();
    }
    boff[t] = s[t] - v;   // exclusive
}

__global__ __launch_bounds__(256) void emit_k(const int* __restrict__ cnt,
                                              const int* __restrict__ boff,
                                              int* __restrict__ rowptr,
                                              int* __restrict__ cursor,
                                              float* __restrict__ dinv)
{
    __shared__ int s[256];
    int b = blockIdx.x, t = threadIdx.x;
    int i = b * 256 + t;
    int v = (i < NN) ? cnt[i] : 0;
    s[t] = v;
    __syncthreads();
    #pragma unroll
    for (int off = 1; off < 256; off <<= 1) {
        int add = (t >= off) ? s[t - off] : 0;
        __syncthreads();
        s[t] += add;
        __syncthreads();
    }
    int run = boff[b] + s[t] - v;   // exclusive prefix
    if (i < NN) {
        rowptr[i] = run;
        cursor[i] = run;
        dinv[i]   = rsqrtf((float)(v + 1));   // deg includes self-loop
        if (i == NN - 1) rowptr[NN] = run + v;
    }
}

// fill src-only records — ONE scattered 4B write per edge (span 3.2 MB: merges in L2)
__global__ void fill_k(const int* __restrict__ ei, int* __restrict__ cursor,
                       int* __restrict__ esrc)
{
    int e = blockIdx.x * 256 + threadIdx.x;
    if (e < EE) {
        int r = ei[e];          // source
        int c = ei[EE + e];     // target
        int p = atomicAdd(&cursor[c], 1);
        esrc[p] = r;
    }
}

// edge-parallel: ebuf2[e] = {batch[src], src}  (coalesced; batch L2-resident)
__global__ void pb_k(const int* __restrict__ esrc, const int* __restrict__ batch,
                     int2* __restrict__ ebuf2)
{
    int e = blockIdx.x * 256 + threadIdx.x;
    if (e < EE) {
        int r = esrc[e];
        ebuf2[e] = make_int2(batch[r], r);
    }
}

// ---------- GEMM: out sliced [8][rows][16]; in plain rows (S=0) or sliced (S=1) ----------
template<int SLICED_IN>
__global__ __launch_bounds__(256) void gemm128s_k(const float* __restrict__ in,
                                                  const float* __restrict__ W,
                                                  float* __restrict__ out,
                                                  int rows)
{
    int r = blockIdx.x * 256 + threadIdx.x;
    if (r >= rows) return;
    int c0 = blockIdx.y * 32;

    float acc[32];
    #pragma unroll
    for (int j = 0; j < 32; j++) acc[j] = 0.f;

    for (int k0 = 0; k0 < 128; k0 += 8) {
        const float* bp = SLICED_IN
            ? in + ((size_t)(k0 >> 4) * rows + r) * 16 + (k0 & 8)
            : in + (size_t)r * 128 + k0;
        float4 ra = *(const float4*)(bp);
        float4 rb = *(const float4*)(bp + 4);
        float rr[8] = {ra.x, ra.y, ra.z, ra.w, rb.x, rb.y, rb.z, rb.w};
        #pragma unroll
        for (int kk = 0; kk < 8; kk++) {
            const float* wr = W + (size_t)(k0 + kk) * 128 + c0;   // wave-uniform -> s_load
            #pragma unroll
            for (int j = 0; j < 32; j++) acc[j] = fmaf(rr[kk], wr[j], acc[j]);
        }
    }
    int s0 = c0 >> 4;                       // covers slices s0, s0+1
    float* o0 = out + ((size_t)s0 * rows + r) * 16;
    float* o1 = out + ((size_t)(s0 + 1) * rows + r) * 16;
    #pragma unroll
    for (int j = 0; j < 4; j++) {
        *(float4*)(o0 + j * 4) = make_float4(acc[4*j], acc[4*j+1], acc[4*j+2], acc[4*j+3]);
        *(float4*)(o1 + j * 4) = make_float4(acc[16+4*j], acc[17+4*j], acc[18+4*j], acc[19+4*j]);
    }
}

// ---------- XCD-sliced aggregation ----------
// grid (8, ceil(NN/NPB)): blockIdx.x = slice -> XCD via linear-id%8 round-robin.
// Per-XCD working set: A slice 3.2 MB + dinv 0.2 MB -> fits 4 MB L2.
// 64 threads = 4 edge-groups x 16 feat lanes; shfl butterfly over groups.
__global__ __launch_bounds__(64) void aggs_k(const float* __restrict__ As,
                                             const int* __restrict__ rowptr,
                                             const int* __restrict__ esrc,
                                             const float* __restrict__ dinv,
                                             const float* __restrict__ bias,
                                             float* __restrict__ Bs,
                                             int relu)
{
    int sl = blockIdx.x;                  // slice 0..7
    int l  = threadIdx.x & 15;            // feat within slice
    int g  = threadIdx.x >> 4;            // edge group 0..3
    const float* Asl = As + (size_t)sl * NN * 16;
    float* Bsl = Bs + (size_t)sl * NN * 16;
    float bv = bias[sl * 16 + l];

    int i0 = blockIdx.y * NPB;
    int i1 = min(i0 + NPB, NN);
    for (int i = i0; i < i1; i++) {
        float di = dinv[i];
        int e0 = rowptr[i], e1 = rowptr[i + 1];
        float v = 0.f;
        if (g == 0) v = di * di * Asl[(size_t)i * 16 + l];   // self-loop term
        for (int ea = e0 + 2 * g; ea < e1; ea += 8) {        // 2 edges per group per iter
            int sA = __builtin_nontemporal_load(esrc + ea);
            int sB = (ea + 1 < e1) ? __builtin_nontemporal_load(esrc + ea + 1) : sA;
            float nA = dinv[sA] * di;
            float nB = dinv[sB] * di;
            float wA = Asl[(size_t)sA * 16 + l];
            float wB = Asl[(size_t)sB * 16 + l];
            v += nA * wA;
            if (ea + 1 < e1) v += nB * wB;
        }
        v += __shfl_xor(v, 16);
        v += __shfl_xor(v, 32);
        if (g == 0) {
            float o = v + bv;
            if (relu) o = fmaxf(o, 0.f);
            __builtin_nontemporal_store(o, Bsl + (size_t)i * 16 + l);  // don't evict A slice
        }
    }
}

// conv3 aggregation: zz [G][128] is L2-resident everywhere; ebuf2 = {batch[src], src}
__global__ __launch_bounds__(64) void agg_out_k(const float* __restrict__ zz,
                                                const int* __restrict__ batch,
                                                const int* __restrict__ rowptr,
                                                const int2* __restrict__ ebuf2,
                                                const float* __restrict__ dinv,
                                                const float* __restrict__ bias,
                                                float* __restrict__ out)
{
    int i = blockIdx.x;
    int f = threadIdx.x;
    const float2* zp = (const float2*)zz;
    float di = dinv[i];
    float sn = di * di;
    float2 v = zp[(size_t)batch[i] * 64 + f];
    float a0 = sn * v.x, a1 = sn * v.y;
    int e0 = rowptr[i], e1 = rowptr[i + 1];
    int e = e0;
    for (; e + 3 < e1; e += 4) {
        int2 r0 = ebuf2[e],     r1 = ebuf2[e + 1];
        int2 r2 = ebuf2[e + 2], r3 = ebuf2[e + 3];
        float2 w0 = zp[(size_t)r0.x * 64 + f];
        float2 w1 = zp[(size_t)r1.x * 64 + f];
        float2 w2 = zp[(size_t)r2.x * 64 + f];
        float2 w3 = zp[(size_t)r3.x * 64 + f];
        float n0 = dinv[r0.y] * di, n1 = dinv[r1.y] * di;
        float n2 = dinv[r2.y] * di, n3 = dinv[r3.y] * di;
        a0 += n0 * w0.x; a1 += n0 * w0.y;
        a0 += n1 * w1.x; a1 += n1 * w1.y;
        a0 += n2 * w2.x; a1 += n2 * w2.y;
        a0 += n3 * w3.x; a1 += n3 * w3.y;
    }
    for (; e < e1; e++) {
        int2 r = ebuf2[e];
        float nm = dinv[r.y] * di;
        float2 w = zp[(size_t)r.x * 64 + f];
        a0 += nm * w.x; a1 += nm * w.y;
    }
    float2 b = ((const float2*)bias)[f];
    a0 += b.x; a1 += b.y;
    ((float2*)out)[(size_t)i * 64 + f] = make_float2(a0, a1);
}

// ---------- pooling (parallel, sliced input) ----------
__global__ __launch_bounds__(128) void pool2_k(const float* __restrict__ Bs,
                                               const int* __restrict__ batch,
                                               float* __restrict__ pooled)
{
    int g = blockIdx.x;
    int c = blockIdx.y;
    int f = threadIdx.x;                       // 0..127
    int sl = f >> 4, off = f & 15;
    const float* Bsl = Bs + ((size_t)sl * NN) * 16 + off;
    int bs = lowerb(batch, NN, g);
    int be = lowerb(batch, NN, g + 1);
    int len = be - bs;
    int cs = bs + (int)(((long long)len * c) / PCH);
    int ce = bs + (int)(((long long)len * (c + 1)) / PCH);
    float a = 0.f;
    for (int i = cs; i < ce; i++) a += Bsl[(size_t)i * 16];
    if (ce > cs) atomicAdd(&pooled[(size_t)g * 128 + f], a);
}

// ---------- fc: latent = relu(pooled @ fcW + fcb); writes latent to d_out too ----------
__global__ __launch_bounds__(64) void fc_k(const float* __restrict__ pooled,
                                           const float* __restrict__ fcW,    // [128][64]
                                           const float* __restrict__ fcb,
                                           float* __restrict__ latentf,
                                           float* __restrict__ lat_out)
{
    int g = blockIdx.x, l = threadIdx.x;
    const float* p = pooled + (size_t)g * 128;
    float a = fcb[l];
    #pragma unroll 8
    for (int k = 0; k < 128; k++) a = fmaf(p[k], fcW[(size_t)k * 64 + l], a);
    a = fmaxf(a, 0.f);
    latentf[(size_t)g * 64 + l] = a;
    lat_out[(size_t)g * 64 + l] = a;
}

// ---------- decoder + W3 transform: zz = relu(latent@decW + decb) @ W3 ----------
__global__ __launch_bounds__(128) void dec_k(const float* __restrict__ latentf,
                                             const float* __restrict__ decW,  // [64][128]
                                             const float* __restrict__ decb,
                                             const float* __restrict__ W3,    // [128][128]
                                             float* __restrict__ zz)
{
    __shared__ float zs[128];
    int g = blockIdx.x, c = threadIdx.x;
    const float* lat = latentf + (size_t)g * 64;
    {
        float a = decb[c];
        #pragma unroll 8
        for (int k = 0; k < 64; k++) a = fmaf(lat[k], decW[(size_t)k * 128 + c], a);
        zs[c] = fmaxf(a, 0.f);
    }
    __syncthreads();
    float o = 0.f;
    #pragma unroll 8
    for (int k = 0; k < 128; k++) o = fmaf(zs[k], W3[(size_t)k * 128 + c], o);
    zz[(size_t)g * 128 + c] = o;
}

extern "C" void kernel_launch(void* const* d_in, const int* in_sizes, int n_in,
                              void* d_out, int out_size, void* d_ws, size_t ws_size,
                              hipStream_t stream)
{
    const float* x     = (const float*)d_in[0];
    const int*   ei    = (const int*)d_in[1];
    const int*   batch = (const int*)d_in[2];
    const float* W1  = (const float*)d_in[3];
    const float* b1  = (const float*)d_in[4];
    const float* W2  = (const float*)d_in[5];
    const float* b2  = (const float*)d_in[6];
    const float* fcW = (const float*)d_in[7];
    const float* fcb = (const float*)d_in[8];
    const float* decW= (const float*)d_in[9];
    const float* decb= (const float*)d_in[10];
    const float* W3  = (const float*)d_in[11];
    const float* b3  = (const float*)d_in[12];

    char* ws = (char*)d_ws;
    size_t off = 0;
    auto alloc = [&](size_t bytes) -> char* {
        char* p = ws + off;
        off = (off + bytes + 255) & ~(size_t)255;
        return p;
    };
    float* dinv     = (float*)alloc((size_t)NN * 4);
    int*   cnt      = (int*)alloc((size_t)NN * 4);
    int*   rowptr   = (int*)alloc((size_t)(NN + 1) * 4);
    int*   cursor   = (int*)alloc((size_t)NN * 4);
    int*   bsum     = (int*)alloc((size_t)NBLK * 4);
    int*   boff     = (int*)alloc(256 * 4);
    int*   esrc     = (int*)alloc((size_t)EE * 4);           // CSR src indices
    float* pooled   = (float*)alloc((size_t)GG * 128 * 4);
    float* latentf  = (float*)alloc((size_t)GG * 64 * 4);
    float* zz       = (float*)alloc((size_t)GG * 128 * 4);
    float* A        = (float*)alloc((size_t)NN * 128 * 4);   // transformed t (sliced)
    float* B        = (float*)alloc((size_t)NN * 128 * 4);   // hidden h (sliced)
    // ebuf2 aliases A: built only AFTER the 2nd aggs has consumed A
    int2*  ebuf2    = (int2*)A;

    float* recon_out = (float*)d_out;
    float* lat_out   = (float*)d_out + (size_t)NN * 128;

    hipMemsetAsync(cnt, 0, (size_t)NN * 4, stream);
    hipMemsetAsync(pooled, 0, (size_t)GG * 128 * 4, stream);
    count_k<<<(EE + 255) / 256, 256, 0, stream>>>(ei, cnt);
    bsum_k<<<NBLK, 256, 0, stream>>>(cnt, bsum);
    scanb_k<<<1, 256, 0, stream>>>(bsum, boff);
    emit_k<<<NBLK, 256, 0, stream>>>(cnt, boff, rowptr, cursor, dinv);
    fill_k<<<(EE + 255) / 256, 256, 0, stream>>>(ei, cursor, esrc);

    dim3 ggrid((NN + 255) / 256, 4);
    dim3 agrid(8, (NN + NPB - 1) / NPB);     // grid.x = 8 -> slice pinned to XCD (id%8)
    // conv1: t1 = x @ W1 -> A(sliced) ; h1 = relu(agg(A) + b1) -> B(sliced)
    gemm128s_k<0><<<ggrid, 256, 0, stream>>>(x, W1, A, NN);
    aggs_k<<<agrid, 64, 0, stream>>>(A, rowptr, esrc, dinv, b1, B, 1);
    // conv2: t2 = h1 @ W2 -> A ; h2 = relu(agg(A) + b2) -> B
    gemm128s_k<1><<<ggrid, 256, 0, stream>>>(B, W2, A, NN);
    aggs_k<<<agrid, 64, 0, stream>>>(A, rowptr, esrc, dinv, b2, B, 1);
    // A is now free -> build ebuf2 = {batch[src], src} in its space
    pb_k<<<(EE + 255) / 256, 256, 0, stream>>>(esrc, batch, ebuf2);
    // pool + fc (latent out) + decoder(+W3 transform)
    pool2_k<<<dim3(GG, PCH), 128, 0, stream>>>(B, batch, pooled);
    fc_k<<<GG, 64, 0, stream>>>(pooled, fcW, fcb, latentf, lat_out);
    dec_k<<<GG, 128, 0, stream>>>(latentf, decW, decb, W3, zz);
    // conv3 -> recon
    agg_out_k<<<NN, 64, 0, stream>>>(zz, batch, rowptr, ebuf2, dinv,
                                     b3, recon_out);
}

// Round 7
// 615.066 us; speedup vs baseline: 1.2545x; 1.2545x over previous
//
#include <hip/hip_runtime.h>

// Problem constants
static constexpr int NN   = 50000;
static constexpr int EE   = 800000;
static constexpr int GG   = 256;
static constexpr int NBLK = (NN + 255) / 256;   // 196
static constexpr int PCH  = 16;                 // pooling chunks per graph

// ---------- helpers ----------
__device__ __forceinline__ int lowerb(const int* __restrict__ b, int n, int v) {
    int lo = 0, hi = n;
    while (lo < hi) { int m = (lo + hi) >> 1; if (b[m] < v) lo = m + 1; else hi = m; }
    return lo;
}

// ---------- CSR build (by target node = col) ----------
__global__ void count_k(const int* __restrict__ ei, int* __restrict__ cnt)
{
    int e = blockIdx.x * 256 + threadIdx.x;
    if (e < EE) atomicAdd(&cnt[ei[EE + e]], 1);
}

__global__ __launch_bounds__(256) void bsum_k(const int* __restrict__ cnt, int* __restrict__ bsum)
{
    __shared__ int s[256];
    int b = blockIdx.x, t = threadIdx.x;
    int i = b * 256 + t;
    s[t] = (i < NN) ? cnt[i] : 0;
    __syncthreads();
    #pragma unroll
    for (int off = 128; off > 0; off >>= 1) {
        if (t < off) s[t] += s[t + off];
        __syncthreads();
    }
    if (t == 0) bsum[b] = s[0];
}

__global__ __launch_bounds__(256) void scanb_k(const int* __restrict__ bsum, int* __restrict__ boff)
{
    __shared__ int s[256];
    int t = threadIdx.x;
    int v = (t < NBLK) ? bsum[t] : 0;
    s[t] = v;
    __syncthreads();
    #pragma unroll
    for (int off = 1; off < 256; off <<= 1) {
        int add = (t >= off) ? s[t - off] : 0;
        __syncthreads();
        s[t] += add;
        __syncthreads();
    }
    boff[t] = s[t] - v;   // exclusive
}

__global__ __launch_bounds__(256) void emit_k(const int* __restrict__ cnt,
                                              const int* __restrict__ boff,
                                              int* __restrict__ rowptr,
                                              int* __restrict__ cursor,
                                              float* __restrict__ dinv)
{
    __shared__ int s[256];
    int b = blockIdx.x, t = threadIdx.x;
    int i = b * 256 + t;
    int v = (i < NN) ? cnt[i] : 0;
    s[t] = v;
    __syncthreads();
    #pragma unroll
    for (int off = 1; off < 256; off <<= 1) {
        int add = (t >= off) ? s[t - off] : 0;
        __syncthreads();
        s[t] += add;
        __syncthreads();
    }
    int run = boff[b] + s[t] - v;   // exclusive prefix
    if (i < NN) {
        rowptr[i] = run;
        cursor[i] = run;
        dinv[i]   = rsqrtf((float)(v + 1));   // deg includes self-loop
        if (i == NN - 1) rowptr[NN] = run + v;
    }
}

// fill ushort src records — scattered 2B writes over 1.6 MB span (merges in L2)
__global__ void fill_k(const int* __restrict__ ei, int* __restrict__ cursor,
                       unsigned short* __restrict__ esrc)
{
    int e = blockIdx.x * 256 + threadIdx.x;
    if (e < EE) {
        int r = ei[e];          // source (< 50000 < 65536)
        int c = ei[EE + e];     // target
        int p = atomicAdd(&cursor[c], 1);
        esrc[p] = (unsigned short)r;
    }
}

// edge-parallel: ep[e] = src | batch[src]<<16  (coalesced; batch L2-resident)
__global__ void pb2_k(const unsigned short* __restrict__ esrc, const int* __restrict__ batch,
                      unsigned int* __restrict__ ep)
{
    int e = blockIdx.x * 256 + threadIdx.x;
    if (e < EE) {
        unsigned int s = esrc[e];
        ep[e] = s | ((unsigned int)batch[s] << 16);
    }
}

// ---------- GEMM: out sliced [8][rows][16]; in plain rows (S=0) or sliced (S=1) ----------
template<int SLICED_IN>
__global__ __launch_bounds__(256) void gemm128s_k(const float* __restrict__ in,
                                                  const float* __restrict__ W,
                                                  float* __restrict__ out,
                                                  int rows)
{
    int r = blockIdx.x * 256 + threadIdx.x;
    if (r >= rows) return;
    int c0 = blockIdx.y * 32;

    float acc[32];
    #pragma unroll
    for (int j = 0; j < 32; j++) acc[j] = 0.f;

    for (int k0 = 0; k0 < 128; k0 += 8) {
        const float* bp = SLICED_IN
            ? in + ((size_t)(k0 >> 4) * rows + r) * 16 + (k0 & 8)
            : in + (size_t)r * 128 + k0;
        float4 ra = *(const float4*)(bp);
        float4 rb = *(const float4*)(bp + 4);
        float rr[8] = {ra.x, ra.y, ra.z, ra.w, rb.x, rb.y, rb.z, rb.w};
        #pragma unroll
        for (int kk = 0; kk < 8; kk++) {
            const float* wr = W + (size_t)(k0 + kk) * 128 + c0;   // wave-uniform -> s_load
            #pragma unroll
            for (int j = 0; j < 32; j++) acc[j] = fmaf(rr[kk], wr[j], acc[j]);
        }
    }
    int s0 = c0 >> 4;                       // covers slices s0, s0+1
    float* o0 = out + ((size_t)s0 * rows + r) * 16;
    float* o1 = out + ((size_t)(s0 + 1) * rows + r) * 16;
    #pragma unroll
    for (int j = 0; j < 4; j++) {
        *(float4*)(o0 + j * 4) = make_float4(acc[4*j], acc[4*j+1], acc[4*j+2], acc[4*j+3]);
        *(float4*)(o1 + j * 4) = make_float4(acc[16+4*j], acc[17+4*j], acc[18+4*j], acc[19+4*j]);
    }
}

// ---------- XCD-sliced aggregation, high-MLP version ----------
// grid (8, NN/16): blockIdx.x = slice -> XCD (linear id % 8). block 256 = 16 groups
// x 16 lanes; each group owns ONE node; edge loop unrolled x4 -> 16 independent
// 2-deep gather chains per wave. Resident per XCD: slice 3.2 MB + dinv/rowptr
// 0.4 MB (esrc NT-streamed, 1.6 MB).
__global__ __launch_bounds__(256) void aggs2_k(const float* __restrict__ As,
                                               const int* __restrict__ rowptr,
                                               const unsigned short* __restrict__ esrc,
                                               const float* __restrict__ dinv,
                                               const float* __restrict__ bias,
                                               float* __restrict__ Bs,
                                               int relu)
{
    int sl = blockIdx.x;                  // slice 0..7
    int g  = threadIdx.x >> 4;            // group = node-in-block
    int l  = threadIdx.x & 15;            // feat within slice
    int i  = blockIdx.y * 16 + g;         // NN = 50000 = 3125*16 exact
    const float* Asl = As + (size_t)sl * NN * 16;
    float di = dinv[i];
    float acc = di * di * Asl[(size_t)i * 16 + l];   // self-loop term
    int e0 = rowptr[i], e1 = rowptr[i + 1];
    int e = e0;
    for (; e + 3 < e1; e += 4) {
        int s0 = __builtin_nontemporal_load(esrc + e);
        int s1 = __builtin_nontemporal_load(esrc + e + 1);
        int s2 = __builtin_nontemporal_load(esrc + e + 2);
        int s3 = __builtin_nontemporal_load(esrc + e + 3);
        float w0 = Asl[(size_t)s0 * 16 + l];
        float w1 = Asl[(size_t)s1 * 16 + l];
        float w2 = Asl[(size_t)s2 * 16 + l];
        float w3 = Asl[(size_t)s3 * 16 + l];
        acc = fmaf(dinv[s0] * di, w0, acc);
        acc = fmaf(dinv[s1] * di, w1, acc);
        acc = fmaf(dinv[s2] * di, w2, acc);
        acc = fmaf(dinv[s3] * di, w3, acc);
    }
    for (; e < e1; e++) {
        int s = __builtin_nontemporal_load(esrc + e);
        acc = fmaf(dinv[s] * di, Asl[(size_t)s * 16 + l], acc);
    }
    float o = acc + bias[sl * 16 + l];
    if (relu) o = fmaxf(o, 0.f);
    __builtin_nontemporal_store(o, Bs + ((size_t)sl * NN + i) * 16 + l);
}

// conv3 aggregation, same structure; gathers from L2-resident zz [G][128];
// ep = {src | batch[src]<<16} NT-streamed
__global__ __launch_bounds__(256) void agg_out2_k(const float* __restrict__ zz,
                                                  const int* __restrict__ batch,
                                                  const int* __restrict__ rowptr,
                                                  const unsigned int* __restrict__ ep,
                                                  const float* __restrict__ dinv,
                                                  const float* __restrict__ bias,
                                                  float* __restrict__ out)
{
    int sl = blockIdx.x;
    int g  = threadIdx.x >> 4;
    int l  = threadIdx.x & 15;
    int i  = blockIdx.y * 16 + g;
    int fo = sl * 16 + l;
    float di = dinv[i];
    float acc = di * di * zz[(size_t)batch[i] * 128 + fo];
    int e0 = rowptr[i], e1 = rowptr[i + 1];
    int e = e0;
    for (; e + 3 < e1; e += 4) {
        unsigned int p0 = __builtin_nontemporal_load(ep + e);
        unsigned int p1 = __builtin_nontemporal_load(ep + e + 1);
        unsigned int p2 = __builtin_nontemporal_load(ep + e + 2);
        unsigned int p3 = __builtin_nontemporal_load(ep + e + 3);
        float w0 = zz[(size_t)(p0 >> 16) * 128 + fo];
        float w1 = zz[(size_t)(p1 >> 16) * 128 + fo];
        float w2 = zz[(size_t)(p2 >> 16) * 128 + fo];
        float w3 = zz[(size_t)(p3 >> 16) * 128 + fo];
        acc = fmaf(dinv[p0 & 0xffffu] * di, w0, acc);
        acc = fmaf(dinv[p1 & 0xffffu] * di, w1, acc);
        acc = fmaf(dinv[p2 & 0xffffu] * di, w2, acc);
        acc = fmaf(dinv[p3 & 0xffffu] * di, w3, acc);
    }
    for (; e < e1; e++) {
        unsigned int p = __builtin_nontemporal_load(ep + e);
        acc = fmaf(dinv[p & 0xffffu] * di, zz[(size_t)(p >> 16) * 128 + fo], acc);
    }
    __builtin_nontemporal_store(acc + bias[fo], out + (size_t)i * 128 + fo);
}

// ---------- pooling (parallel, sliced input) ----------
__global__ __launch_bounds__(128) void pool2_k(const float* __restrict__ Bs,
                                               const int* __restrict__ batch,
                                               float* __restrict__ pooled)
{
    int g = blockIdx.x;
    int c = blockIdx.y;
    int f = threadIdx.x;                       // 0..127
    int sl = f >> 4, off = f & 15;
    const float* Bsl = Bs + ((size_t)sl * NN) * 16 + off;
    int bs = lowerb(batch, NN, g);
    int be = lowerb(batch, NN, g + 1);
    int len = be - bs;
    int cs = bs + (int)(((long long)len * c) / PCH);
    int ce = bs + (int)(((long long)len * (c + 1)) / PCH);
    float a = 0.f;
    for (int i = cs; i < ce; i++) a += Bsl[(size_t)i * 16];
    if (ce > cs) atomicAdd(&pooled[(size_t)g * 128 + f], a);
}

// ---------- fused fc + decoder + W3 transform ----------
// latent = relu(pooled@fcW + fcb) ; z = relu(latent@decW + decb) ; zz = z@W3
__global__ __launch_bounds__(128) void fcdec_k(const float* __restrict__ pooled,
                                               const float* __restrict__ fcW,   // [128][64]
                                               const float* __restrict__ fcb,
                                               const float* __restrict__ decW,  // [64][128]
                                               const float* __restrict__ decb,
                                               const float* __restrict__ W3,    // [128][128]
                                               float* __restrict__ lat_out,
                                               float* __restrict__ zz)
{
    __shared__ float lat[64];
    __shared__ float zs[128];
    int g = blockIdx.x, c = threadIdx.x;
    if (c < 64) {
        const float* p = pooled + (size_t)g * 128;   // uniform scalar loads
        float a = fcb[c];
        #pragma unroll 8
        for (int k = 0; k < 128; k++) a = fmaf(p[k], fcW[(size_t)k * 64 + c], a);
        a = fmaxf(a, 0.f);
        lat[c] = a;
        lat_out[(size_t)g * 64 + c] = a;
    }
    __syncthreads();
    {
        float a = decb[c];
        #pragma unroll 8
        for (int k = 0; k < 64; k++) a = fmaf(lat[k], decW[(size_t)k * 128 + c], a);
        zs[c] = fmaxf(a, 0.f);
    }
    __syncthreads();
    float o = 0.f;
    #pragma unroll 8
    for (int k = 0; k < 128; k++) o = fmaf(zs[k], W3[(size_t)k * 128 + c], o);
    zz[(size_t)g * 128 + c] = o;
}

extern "C" void kernel_launch(void* const* d_in, const int* in_sizes, int n_in,
                              void* d_out, int out_size, void* d_ws, size_t ws_size,
                              hipStream_t stream)
{
    const float* x     = (const float*)d_in[0];
    const int*   ei    = (const int*)d_in[1];
    const int*   batch = (const int*)d_in[2];
    const float* W1  = (const float*)d_in[3];
    const float* b1  = (const float*)d_in[4];
    const float* W2  = (const float*)d_in[5];
    const float* b2  = (const float*)d_in[6];
    const float* fcW = (const float*)d_in[7];
    const float* fcb = (const float*)d_in[8];
    const float* decW= (const float*)d_in[9];
    const float* decb= (const float*)d_in[10];
    const float* W3  = (const float*)d_in[11];
    const float* b3  = (const float*)d_in[12];

    char* ws = (char*)d_ws;
    size_t off = 0;
    auto alloc = [&](size_t bytes) -> char* {
        char* p = ws + off;
        off = (off + bytes + 255) & ~(size_t)255;
        return p;
    };
    float* dinv     = (float*)alloc((size_t)NN * 4);
    int*   cnt      = (int*)alloc((size_t)NN * 4);
    int*   rowptr   = (int*)alloc((size_t)(NN + 1) * 4);
    int*   cursor   = (int*)alloc((size_t)NN * 4);
    int*   bsum     = (int*)alloc((size_t)NBLK * 4);
    int*   boff     = (int*)alloc(256 * 4);
    unsigned short* esrc = (unsigned short*)alloc((size_t)EE * 2);  // CSR src (ushort)
    float* pooled   = (float*)alloc((size_t)GG * 128 * 4);
    float* latentf  = (float*)alloc((size_t)GG * 64 * 4);   // (unused; lat goes to d_out)
    float* zz       = (float*)alloc((size_t)GG * 128 * 4);
    float* A        = (float*)alloc((size_t)NN * 128 * 4);  // transformed t (sliced)
    float* B        = (float*)alloc((size_t)NN * 128 * 4);  // hidden h (sliced)
    // ep aliases A: built only AFTER the 2nd aggs2 has consumed A
    unsigned int* ep = (unsigned int*)A;
    (void)latentf;

    float* recon_out = (float*)d_out;
    float* lat_out   = (float*)d_out + (size_t)NN * 128;

    hipMemsetAsync(cnt, 0, (size_t)NN * 4, stream);
    hipMemsetAsync(pooled, 0, (size_t)GG * 128 * 4, stream);
    count_k<<<(EE + 255) / 256, 256, 0, stream>>>(ei, cnt);
    bsum_k<<<NBLK, 256, 0, stream>>>(cnt, bsum);
    scanb_k<<<1, 256, 0, stream>>>(bsum, boff);
    emit_k<<<NBLK, 256, 0, stream>>>(cnt, boff, rowptr, cursor, dinv);
    fill_k<<<(EE + 255) / 256, 256, 0, stream>>>(ei, cursor, esrc);

    dim3 ggrid((NN + 255) / 256, 4);
    dim3 agrid(8, NN / 16);                  // grid.x = 8 -> slice pinned to XCD (id%8)
    // conv1: t1 = x @ W1 -> A(sliced) ; h1 = relu(agg(A) + b1) -> B(sliced)
    gemm128s_k<0><<<ggrid, 256, 0, stream>>>(x, W1, A, NN);
    aggs2_k<<<agrid, 256, 0, stream>>>(A, rowptr, esrc, dinv, b1, B, 1);
    // conv2: t2 = h1 @ W2 -> A ; h2 = relu(agg(A) + b2) -> B
    gemm128s_k<1><<<ggrid, 256, 0, stream>>>(B, W2, A, NN);
    aggs2_k<<<agrid, 256, 0, stream>>>(A, rowptr, esrc, dinv, b2, B, 1);
    // A is now free -> build ep = {src | batch[src]<<16} in its space
    pb2_k<<<(EE + 255) / 256, 256, 0, stream>>>(esrc, batch, ep);
    // pool + fused fc/dec (latent out, zz)
    pool2_k<<<dim3(GG, PCH), 128, 0, stream>>>(B, batch, pooled);
    fcdec_k<<<GG, 128, 0, stream>>>(pooled, fcW, fcb, decW, decb, W3, lat_out, zz);
    // conv3 -> recon
    agg_out2_k<<<agrid, 256, 0, stream>>>(zz, batch, rowptr, ep, dinv, b3, recon_out);
}

// Round 9
// 476.130 us; speedup vs baseline: 1.6206x; 1.2918x over previous
//
#include <hip/hip_runtime.h>

// Problem constants
static constexpr int NN   = 50000;
static constexpr int EE   = 800000;
static constexpr int GG   = 256;
static constexpr int NBLK = (NN + 255) / 256;   // 196
static constexpr int PCH  = 16;                 // pooling chunks per graph

typedef float f32x2 __attribute__((ext_vector_type(2)));   // native vec for NT store

// ---------- helpers ----------
__device__ __forceinline__ int lowerb(const int* __restrict__ b, int n, int v) {
    int lo = 0, hi = n;
    while (lo < hi) { int m = (lo + hi) >> 1; if (b[m] < v) lo = m + 1; else hi = m; }
    return lo;
}

// ---------- CSR build (by target node = col) ----------
__global__ void count_k(const int* __restrict__ ei, int* __restrict__ cnt)
{
    int e = blockIdx.x * 256 + threadIdx.x;
    if (e < EE) atomicAdd(&cnt[ei[EE + e]], 1);
}

__global__ __launch_bounds__(256) void bsum_k(const int* __restrict__ cnt, int* __restrict__ bsum)
{
    __shared__ int s[256];
    int b = blockIdx.x, t = threadIdx.x;
    int i = b * 256 + t;
    s[t] = (i < NN) ? cnt[i] : 0;
    __syncthreads();
    #pragma unroll
    for (int off = 128; off > 0; off >>= 1) {
        if (t < off) s[t] += s[t + off];
        __syncthreads();
    }
    if (t == 0) bsum[b] = s[0];
}

__global__ __launch_bounds__(256) void scanb_k(const int* __restrict__ bsum, int* __restrict__ boff)
{
    __shared__ int s[256];
    int t = threadIdx.x;
    int v = (t < NBLK) ? bsum[t] : 0;
    s[t] = v;
    __syncthreads();
    #pragma unroll
    for (int off = 1; off < 256; off <<= 1) {
        int add = (t >= off) ? s[t - off] : 0;
        __syncthreads();
        s[t] += add;
        __syncthreads();
    }
    boff[t] = s[t] - v;   // exclusive
}

__global__ __launch_bounds__(256) void emit_k(const int* __restrict__ cnt,
                                              const int* __restrict__ boff,
                                              int* __restrict__ rowptr,
                                              int* __restrict__ cursor,
                                              float* __restrict__ dinv)
{
    __shared__ int s[256];
    int b = blockIdx.x, t = threadIdx.x;
    int i = b * 256 + t;
    int v = (i < NN) ? cnt[i] : 0;
    s[t] = v;
    __syncthreads();
    #pragma unroll
    for (int off = 1; off < 256; off <<= 1) {
        int add = (t >= off) ? s[t - off] : 0;
        __syncthreads();
        s[t] += add;
        __syncthreads();
    }
    int run = boff[b] + s[t] - v;   // exclusive prefix
    if (i < NN) {
        rowptr[i] = run;
        cursor[i] = run;
        dinv[i]   = rsqrtf((float)(v + 1));   // deg includes self-loop
        if (i == NN - 1) rowptr[NN] = run + v;
    }
}

// fill ushort src records — scattered 2B writes over 1.6 MB span (merges in L2)
__global__ void fill_k(const int* __restrict__ ei, int* __restrict__ cursor,
                       unsigned short* __restrict__ esrc)
{
    int e = blockIdx.x * 256 + threadIdx.x;
    if (e < EE) {
        int r = ei[e];          // source (< 50000 < 65536)
        int c = ei[EE + e];     // target
        int p = atomicAdd(&cursor[c], 1);
        esrc[p] = (unsigned short)r;
    }
}

// edge-parallel: ep[e] = src | batch[src]<<16  (coalesced; batch L2-resident)
__global__ void pb2_k(const unsigned short* __restrict__ esrc, const int* __restrict__ batch,
                      unsigned int* __restrict__ ep)
{
    int e = blockIdx.x * 256 + threadIdx.x;
    if (e < EE) {
        unsigned int s = esrc[e];
        ep[e] = s | ((unsigned int)batch[s] << 16);
    }
}

// ---------- GEMM: out sliced [8][rows][16]; in plain rows (S=0) or sliced (S=1) ----------
template<int SLICED_IN>
__global__ __launch_bounds__(256) void gemm128s_k(const float* __restrict__ in,
                                                  const float* __restrict__ W,
                                                  float* __restrict__ out,
                                                  int rows)
{
    int r = blockIdx.x * 256 + threadIdx.x;
    if (r >= rows) return;
    int c0 = blockIdx.y * 32;

    float acc[32];
    #pragma unroll
    for (int j = 0; j < 32; j++) acc[j] = 0.f;

    for (int k0 = 0; k0 < 128; k0 += 8) {
        const float* bp = SLICED_IN
            ? in + ((size_t)(k0 >> 4) * rows + r) * 16 + (k0 & 8)
            : in + (size_t)r * 128 + k0;
        float4 ra = *(const float4*)(bp);
        float4 rb = *(const float4*)(bp + 4);
        float rr[8] = {ra.x, ra.y, ra.z, ra.w, rb.x, rb.y, rb.z, rb.w};
        #pragma unroll
        for (int kk = 0; kk < 8; kk++) {
            const float* wr = W + (size_t)(k0 + kk) * 128 + c0;   // wave-uniform -> s_load
            #pragma unroll
            for (int j = 0; j < 32; j++) acc[j] = fmaf(rr[kk], wr[j], acc[j]);
        }
    }
    int s0 = c0 >> 4;                       // covers slices s0, s0+1
    float* o0 = out + ((size_t)s0 * rows + r) * 16;
    float* o1 = out + ((size_t)(s0 + 1) * rows + r) * 16;
    #pragma unroll
    for (int j = 0; j < 4; j++) {
        *(float4*)(o0 + j * 4) = make_float4(acc[4*j], acc[4*j+1], acc[4*j+2], acc[4*j+3]);
        *(float4*)(o1 + j * 4) = make_float4(acc[16+4*j], acc[17+4*j], acc[18+4*j], acc[19+4*j]);
    }
}

// ---------- XCD-sliced aggregation (cached edge stream, unroll x8) ----------
// grid (8, NN/16): blockIdx.x = slice -> XCD (linear id % 8). block 256 = 16 groups
// x 16 lanes; group owns one node. esrc/dinv/slice all L2-cached (NO nontemporal
// loads — R7's NT loads forced 8x HBM re-reads of the edge stream).
__global__ __launch_bounds__(256) void aggs2_k(const float* __restrict__ As,
                                               const int* __restrict__ rowptr,
                                               const unsigned short* __restrict__ esrc,
                                               const float* __restrict__ dinv,
                                               const float* __restrict__ bias,
                                               float* __restrict__ Bs,
                                               int relu)
{
    int sl = blockIdx.x;                  // slice 0..7
    int g  = threadIdx.x >> 4;            // group = node-in-block
    int l  = threadIdx.x & 15;            // feat within slice
    int i  = blockIdx.y * 16 + g;         // NN = 50000 = 3125*16 exact
    const float* Asl = As + (size_t)sl * NN * 16;
    float di = dinv[i];
    float acc = di * di * Asl[(size_t)i * 16 + l];   // self-loop term
    int e0 = rowptr[i], e1 = rowptr[i + 1];
    int e = e0;
    for (; e + 7 < e1; e += 8) {
        int s0 = esrc[e],     s1 = esrc[e + 1];
        int s2 = esrc[e + 2], s3 = esrc[e + 3];
        int s4 = esrc[e + 4], s5 = esrc[e + 5];
        int s6 = esrc[e + 6], s7 = esrc[e + 7];
        float w0 = Asl[(size_t)s0 * 16 + l];
        float w1 = Asl[(size_t)s1 * 16 + l];
        float w2 = Asl[(size_t)s2 * 16 + l];
        float w3 = Asl[(size_t)s3 * 16 + l];
        float w4 = Asl[(size_t)s4 * 16 + l];
        float w5 = Asl[(size_t)s5 * 16 + l];
        float w6 = Asl[(size_t)s6 * 16 + l];
        float w7 = Asl[(size_t)s7 * 16 + l];
        acc = fmaf(dinv[s0] * di, w0, acc);
        acc = fmaf(dinv[s1] * di, w1, acc);
        acc = fmaf(dinv[s2] * di, w2, acc);
        acc = fmaf(dinv[s3] * di, w3, acc);
        acc = fmaf(dinv[s4] * di, w4, acc);
        acc = fmaf(dinv[s5] * di, w5, acc);
        acc = fmaf(dinv[s6] * di, w6, acc);
        acc = fmaf(dinv[s7] * di, w7, acc);
    }
    for (; e < e1; e++) {
        int s = esrc[e];
        acc = fmaf(dinv[s] * di, Asl[(size_t)s * 16 + l], acc);
    }
    float o = acc + bias[sl * 16 + l];
    if (relu) o = fmaxf(o, 0.f);
    __builtin_nontemporal_store(o, Bs + ((size_t)sl * NN + i) * 16 + l);
}

// ---------- conv3 aggregation: R5 shape (node/block, 64 lanes, float2) ----------
// ep[e] block-uniform -> scalar loads; zz [G][128] L2-resident; unroll x8
__global__ __launch_bounds__(64) void agg_out3_k(const float* __restrict__ zz,
                                                 const int* __restrict__ batch,
                                                 const int* __restrict__ rowptr,
                                                 const unsigned int* __restrict__ ep,
                                                 const float* __restrict__ dinv,
                                                 const float* __restrict__ bias,
                                                 float* __restrict__ out)
{
    int i = blockIdx.x;
    int f = threadIdx.x;                   // float2 index, 64 covers 128 feats
    const float2* zp = (const float2*)zz;
    float di = dinv[i];
    float2 v = zp[(size_t)batch[i] * 64 + f];
    float a0 = di * di * v.x, a1 = di * di * v.y;
    int e0 = rowptr[i], e1 = rowptr[i + 1];
    int e = e0;
    for (; e + 7 < e1; e += 8) {
        unsigned int p0 = ep[e],     p1 = ep[e + 1];
        unsigned int p2 = ep[e + 2], p3 = ep[e + 3];
        unsigned int p4 = ep[e + 4], p5 = ep[e + 5];
        unsigned int p6 = ep[e + 6], p7 = ep[e + 7];
        float2 w0 = zp[(size_t)(p0 >> 16) * 64 + f];
        float2 w1 = zp[(size_t)(p1 >> 16) * 64 + f];
        float2 w2 = zp[(size_t)(p2 >> 16) * 64 + f];
        float2 w3 = zp[(size_t)(p3 >> 16) * 64 + f];
        float2 w4 = zp[(size_t)(p4 >> 16) * 64 + f];
        float2 w5 = zp[(size_t)(p5 >> 16) * 64 + f];
        float2 w6 = zp[(size_t)(p6 >> 16) * 64 + f];
        float2 w7 = zp[(size_t)(p7 >> 16) * 64 + f];
        float n0 = dinv[p0 & 0xffffu] * di, n1 = dinv[p1 & 0xffffu] * di;
        float n2 = dinv[p2 & 0xffffu] * di, n3 = dinv[p3 & 0xffffu] * di;
        float n4 = dinv[p4 & 0xffffu] * di, n5 = dinv[p5 & 0xffffu] * di;
        float n6 = dinv[p6 & 0xffffu] * di, n7 = dinv[p7 & 0xffffu] * di;
        a0 += n0 * w0.x; a1 += n0 * w0.y;
        a0 += n1 * w1.x; a1 += n1 * w1.y;
        a0 += n2 * w2.x; a1 += n2 * w2.y;
        a0 += n3 * w3.x; a1 += n3 * w3.y;
        a0 += n4 * w4.x; a1 += n4 * w4.y;
        a0 += n5 * w5.x; a1 += n5 * w5.y;
        a0 += n6 * w6.x; a1 += n6 * w6.y;
        a0 += n7 * w7.x; a1 += n7 * w7.y;
    }
    for (; e < e1; e++) {
        unsigned int p = ep[e];
        float nm = dinv[p & 0xffffu] * di;
        float2 w = zp[(size_t)(p >> 16) * 64 + f];
        a0 += nm * w.x; a1 += nm * w.y;
    }
    float2 b = ((const float2*)bias)[f];
    f32x2 res;
    res.x = a0 + b.x;
    res.y = a1 + b.y;
    __builtin_nontemporal_store(res, (f32x2*)out + (size_t)i * 64 + f);
}

// ---------- pooling (parallel, sliced input) ----------
__global__ __launch_bounds__(128) void pool2_k(const float* __restrict__ Bs,
                                               const int* __restrict__ batch,
                                               float* __restrict__ pooled)
{
    int g = blockIdx.x;
    int c = blockIdx.y;
    int f = threadIdx.x;                       // 0..127
    int sl = f >> 4, off = f & 15;
    const float* Bsl = Bs + ((size_t)sl * NN) * 16 + off;
    int bs = lowerb(batch, NN, g);
    int be = lowerb(batch, NN, g + 1);
    int len = be - bs;
    int cs = bs + (int)(((long long)len * c) / PCH);
    int ce = bs + (int)(((long long)len * (c + 1)) / PCH);
    float a = 0.f;
    for (int i = cs; i < ce; i++) a += Bsl[(size_t)i * 16];
    if (ce > cs) atomicAdd(&pooled[(size_t)g * 128 + f], a);
}

// ---------- fused fc + decoder + W3 transform ----------
__global__ __launch_bounds__(128) void fcdec_k(const float* __restrict__ pooled,
                                               const float* __restrict__ fcW,   // [128][64]
                                               const float* __restrict__ fcb,
                                               const float* __restrict__ decW,  // [64][128]
                                               const float* __restrict__ decb,
                                               const float* __restrict__ W3,    // [128][128]
                                               float* __restrict__ lat_out,
                                               float* __restrict__ zz)
{
    __shared__ float lat[64];
    __shared__ float zs[128];
    int g = blockIdx.x, c = threadIdx.x;
    if (c < 64) {
        const float* p = pooled + (size_t)g * 128;   // uniform scalar loads
        float a = fcb[c];
        #pragma unroll 8
        for (int k = 0; k < 128; k++) a = fmaf(p[k], fcW[(size_t)k * 64 + c], a);
        a = fmaxf(a, 0.f);
        lat[c] = a;
        lat_out[(size_t)g * 64 + c] = a;
    }
    __syncthreads();
    {
        float a = decb[c];
        #pragma unroll 8
        for (int k = 0; k < 64; k++) a = fmaf(lat[k], decW[(size_t)k * 128 + c], a);
        zs[c] = fmaxf(a, 0.f);
    }
    __syncthreads();
    float o = 0.f;
    #pragma unroll 8
    for (int k = 0; k < 128; k++) o = fmaf(zs[k], W3[(size_t)k * 128 + c], o);
    zz[(size_t)g * 128 + c] = o;
}

extern "C" void kernel_launch(void* const* d_in, const int* in_sizes, int n_in,
                              void* d_out, int out_size, void* d_ws, size_t ws_size,
                              hipStream_t stream)
{
    const float* x     = (const float*)d_in[0];
    const int*   ei    = (const int*)d_in[1];
    const int*   batch = (const int*)d_in[2];
    const float* W1  = (const float*)d_in[3];
    const float* b1  = (const float*)d_in[4];
    const float* W2  = (const float*)d_in[5];
    const float* b2  = (const float*)d_in[6];
    const float* fcW = (const float*)d_in[7];
    const float* fcb = (const float*)d_in[8];
    const float* decW= (const float*)d_in[9];
    const float* decb= (const float*)d_in[10];
    const float* W3  = (const float*)d_in[11];
    const float* b3  = (const float*)d_in[12];

    char* ws = (char*)d_ws;
    size_t off = 0;
    auto alloc = [&](size_t bytes) -> char* {
        char* p = ws + off;
        off = (off + bytes + 255) & ~(size_t)255;
        return p;
    };
    float* dinv     = (float*)alloc((size_t)NN * 4);
    int*   cnt      = (int*)alloc((size_t)NN * 4);
    int*   rowptr   = (int*)alloc((size_t)(NN + 1) * 4);
    int*   cursor   = (int*)alloc((size_t)NN * 4);
    int*   bsum     = (int*)alloc((size_t)NBLK * 4);
    int*   boff     = (int*)alloc(256 * 4);
    unsigned short* esrc = (unsigned short*)alloc((size_t)EE * 2);  // CSR src (ushort)
    float* pooled   = (float*)alloc((size_t)GG * 128 * 4);
    float* zz       = (float*)alloc((size_t)GG * 128 * 4);
    float* A        = (float*)alloc((size_t)NN * 128 * 4);  // transformed t (sliced)
    float* B        = (float*)alloc((size_t)NN * 128 * 4);  // hidden h (sliced)
    // ep aliases A: built only AFTER the 2nd aggs2 has consumed A
    unsigned int* ep = (unsigned int*)A;

    float* recon_out = (float*)d_out;
    float* lat_out   = (float*)d_out + (size_t)NN * 128;

    hipMemsetAsync(cnt, 0, (size_t)NN * 4, stream);
    hipMemsetAsync(pooled, 0, (size_t)GG * 128 * 4, stream);
    count_k<<<(EE + 255) / 256, 256, 0, stream>>>(ei, cnt);
    bsum_k<<<NBLK, 256, 0, stream>>>(cnt, bsum);
    scanb_k<<<1, 256, 0, stream>>>(bsum, boff);
    emit_k<<<NBLK, 256, 0, stream>>>(cnt, boff, rowptr, cursor, dinv);
    fill_k<<<(EE + 255) / 256, 256, 0, stream>>>(ei, cursor, esrc);

    dim3 ggrid((NN + 255) / 256, 4);
    dim3 agrid(8, NN / 16);                  // grid.x = 8 -> slice pinned to XCD (id%8)
    // conv1: t1 = x @ W1 -> A(sliced) ; h1 = relu(agg(A) + b1) -> B(sliced)
    gemm128s_k<0><<<ggrid, 256, 0, stream>>>(x, W1, A, NN);
    aggs2_k<<<agrid, 256, 0, stream>>>(A, rowptr, esrc, dinv, b1, B, 1);
    // conv2: t2 = h1 @ W2 -> A ; h2 = relu(agg(A) + b2) -> B
    gemm128s_k<1><<<ggrid, 256, 0, stream>>>(B, W2, A, NN);
    aggs2_k<<<agrid, 256, 0, stream>>>(A, rowptr, esrc, dinv, b2, B, 1);
    // A is now free -> build ep = {src | batch[src]<<16} in its space
    pb2_k<<<(EE + 255) / 256, 256, 0, stream>>>(esrc, batch, ep);
    // pool + fused fc/dec (latent out, zz)
    pool2_k<<<dim3(GG, PCH), 128, 0, stream>>>(B, batch, pooled);
    fcdec_k<<<GG, 128, 0, stream>>>(pooled, fcW, fcb, decW, decb, W3, lat_out, zz);
    // conv3 -> recon (R5-shape node/block kernel)
    agg_out3_k<<<NN, 64, 0, stream>>>(zz, batch, rowptr, ep, dinv, b3, recon_out);
}